// Round 4
// baseline (668.390 us; speedup 1.0000x reference)
//
#include <hip/hip_runtime.h>

// conv2d NCHW/OIHW, stride 1, VALID. x=(64,3,256,256) f32, w=(16,3,3,3), b=(16)
// out=(64,16,254,254) f32.
//
// R4: FLAT output decomposition. Evidence: R0/R1/R3 (three different register
// schedules, 3x different VMEM instr counts) all time identical (~151-157 us
// conv vs 50 us traffic floor) -> limiter is the one invariant: the write
// pattern. oc-reuse designs write 16 scattered 1-KB bursts at 258-KB plane
// stride per wave; the harness's linear poison-fill hits 6.4 TB/s on the same
// chip. This version writes like the fill:
//   - thread i computes out[4i..4i+3] (flat NCHW index): ONE aligned float4
//     nontemporal store, waves perfectly contiguous, planes streamed linearly.
//   - per-thread: one oc -> 9+1 weight/bias loads (4B-aligned vector loads),
//     18 input loads (x stays L2-resident per image; 16x less in-thread reuse
//     is served by L1/L2).
//   - per-c live ranges (9 weights + 6 input cols) -> ~50 VGPR -> 8+ waves/SIMD.
//   - ow0 = 4i mod 254 is always EVEN -> only ow0==252 straddles a row
//     (2 px wrap, ~1 lane per 2 waves): exec-masked per-pixel scalar path.
//     Straddler stores are STILL the same contiguous float4 (flat layout).
// Math order per pixel unchanged (c, kh ascending, kw fma-chain) -> same absmax.

constexpr int N = 64, C = 3, H = 256, W = 256;
constexpr int OC = 16, K = 3, OH = 254, OW = 254;
constexpr unsigned TOTAL = (unsigned)N * OC * OH * OW;   // 66,064,384
constexpr unsigned NTHREADS = TOTAL / 4;                 // 16,516,096 (exact)

typedef float v4a4  __attribute__((ext_vector_type(4), aligned(4)));
typedef float v2a4  __attribute__((ext_vector_type(2), aligned(4)));
typedef float v4a16 __attribute__((ext_vector_type(4), aligned(16)));

__global__ __launch_bounds__(256) void conv3x3_kernel(
    const float* __restrict__ x, const float* __restrict__ w,
    const float* __restrict__ bias, float* __restrict__ out)
{
    unsigned idx = blockIdx.x * 256u + threadIdx.x;
    if (idx >= NTHREADS) return;
    unsigned f = idx * 4u;           // flat output index of pixel 0

    // decode pixel 0: f = ((n*OC + oc)*OH + oh)*OW + ow0
    unsigned q   = f / OW;
    int      ow0 = (int)(f - q * OW);
    int      oh  = (int)(q % OH);
    unsigned t2  = q / OH;
    int      oc  = (int)(t2 & 15u);
    int      nIm = (int)(t2 >> 4);

    float av[4];

    if (ow0 <= OW - 4) {
        // ---- fast path: all 4 pixels in the same (n,oc,oh) row ----
        const float* xb = x + (size_t)nIm * C * H * W;
        const float* wp = w + oc * (C * K * K);
        float b = bias[oc];
        float a0 = b, a1 = b, a2 = b, a3 = b;
        #pragma unroll
        for (int c = 0; c < C; ++c) {
            // 9 weights of this c: 2x dwordx4 + 1 scalar (never OOB: max 431)
            const float* wc = wp + c * 9;
            v4a4 wA = *reinterpret_cast<const v4a4*>(wc);
            v4a4 wB = *reinterpret_cast<const v4a4*>(wc + 4);
            float w8 = wc[8];
            float wk[9] = {wA.x, wA.y, wA.z, wA.w, wB.x, wB.y, wB.z, wB.w, w8};
            #pragma unroll
            for (int kh = 0; kh < K; ++kh) {
                const float* xr = xb + ((size_t)c * H + (oh + kh)) * W + ow0;
                v4a4 lo = *reinterpret_cast<const v4a4*>(xr);
                v2a4 hi = *reinterpret_cast<const v2a4*>(xr + 4);
                float w0 = wk[kh * 3 + 0];
                float w1 = wk[kh * 3 + 1];
                float w2 = wk[kh * 3 + 2];
                a0 += lo.x * w0 + lo.y * w1 + lo.z * w2;
                a1 += lo.y * w0 + lo.z * w1 + lo.w * w2;
                a2 += lo.z * w0 + lo.w * w1 + hi.x * w2;
                a3 += lo.w * w0 + hi.x * w1 + hi.y * w2;
            }
        }
        av[0] = a0; av[1] = a1; av[2] = a2; av[3] = a3;
    } else {
        // ---- slow path (ow0 == 252): per-pixel independent decode ----
        #pragma unroll
        for (int p = 0; p < 4; ++p) {
            unsigned g  = f + p;
            unsigned qq = g / OW;
            int oww = (int)(g - qq * OW);
            int ohh = (int)(qq % OH);
            unsigned tt = qq / OH;
            int occ = (int)(tt & 15u);
            int nn  = (int)(tt >> 4);
            const float* xbp = x + (size_t)nn * C * H * W;
            const float* wpp = w + occ * (C * K * K);
            float acc = bias[occ];
            #pragma unroll
            for (int c = 0; c < C; ++c)
                #pragma unroll
                for (int kh = 0; kh < K; ++kh) {
                    const float* xr = xbp + ((size_t)c * H + (ohh + kh)) * W + oww;
                    const float* wc = wpp + (c * K + kh) * K;
                    acc += xr[0] * wc[0] + xr[1] * wc[1] + xr[2] * wc[2];
                }
            av[p] = acc;
        }
    }

    v4a16 v = {av[0], av[1], av[2], av[3]};
    __builtin_nontemporal_store(v, reinterpret_cast<v4a16*>(out + f));
}

extern "C" void kernel_launch(void* const* d_in, const int* in_sizes, int n_in,
                              void* d_out, int out_size, void* d_ws, size_t ws_size,
                              hipStream_t stream) {
    const float* x    = (const float*)d_in[0];
    const float* w    = (const float*)d_in[1];
    const float* bias = (const float*)d_in[2];
    float* out        = (float*)d_out;

    constexpr unsigned blocks = NTHREADS / 256u;   // 64,516 exact
    conv3x3_kernel<<<blocks, 256, 0, stream>>>(x, w, bias, out);
}

// Round 6
// 321.733 us; speedup vs baseline: 2.0775x; 2.0775x over previous
//
#include <hip/hip_runtime.h>

// conv2d NCHW/OIHW, stride 1, VALID. x=(64,3,256,256) f32, w=(16,3,3,3), b=(16)
// out=(64,16,254,254) f32.
//
// R6 = R5 resubmitted verbatim (R5 bench failed on container infra, kernel
// never ran). Rationale: R4's counters showed FETCH_SIZE = 201 MB for a
// 50 MB input (4x re-fetch). In R0/R1/R3 the linear block order sweeps
// (n,oh) round-robin across the 8 XCDs, so all 8 non-coherent L2s walk the
// SAME x region concurrently -> x is fetched ~8x (=400 MB) and total HBM
// traffic ~664 MB -> ~150 us at mixed-R/W BW. That traffic model (not
// compute, not VMEM count, not store schedule) explains why R0/R1/R3 all
// timed identically. Swizzle gives each XCD a contiguous disjoint
// (n,oh)-chunk: 4064 blocks = 8 XCDs x 508; block (xcd, i) ->
// swz = xcd*508 + i (bijective). Per-XCD x footprint ~6.3 MB, L2-resident
// incl. the 2-row oh-halo -> chip fetch ~50-80 MB.
//
// Everything below the swizzle is byte-identical to R3:
//   - 4 px/thread, wave = one full output row; input: float4+float2 per
//     (c,kh); 27 contiguous s_load weights per oc; aligned 16B nontemporal
//     stores; tail chunk (ow=252) clamps loads in-row and stores 8B.
// Math order per pixel unchanged (c, kh ascending, kw fma-chain) -> same absmax.

constexpr int N = 64, C = 3, H = 256, W = 256;
constexpr int OC = 16, K = 3, OH = 254, OW = 254;
constexpr int PW4 = 64;   // 63 full 4-wide chunks + 1 tail (2-wide) per row

constexpr int NBLOCKS = (N * OH * PW4) / 256;  // 4064
constexpr int NXCD = 8;
constexpr int BLK_PER_XCD = NBLOCKS / NXCD;    // 508 (exact)

typedef float vfloat4 __attribute__((ext_vector_type(4)));
typedef float vfloat2 __attribute__((ext_vector_type(2)));

__global__ __launch_bounds__(256) void conv3x3_kernel(
    const float* __restrict__ x, const float* __restrict__ w,
    const float* __restrict__ bias, float* __restrict__ out)
{
    // XCD-aware swizzle: round-robin dispatch (bid%8 = XCD) -> contiguous
    // per-XCD chunks of the (n,oh) sweep. Bijective since NBLOCKS%8 == 0.
    int bid = blockIdx.x;
    int swz = (bid & (NXCD - 1)) * BLK_PER_XCD + (bid >> 3);
    int idx = swz * 256 + (int)threadIdx.x;

    int chunk = idx & (PW4 - 1);    // 0..63 within a wave -> lane==chunk
    int t  = idx >> 6;
    int oh = t % OH;
    int n  = t / OH;
    int ow = chunk * 4;
    bool tail = (chunk == PW4 - 1); // ow=252: only 2 valid pixels

    const float* xb = x + (size_t)n * C * H * W;

    // Input patch: C*K rows x 6 cols = 54 VGPRs. 16B-aligned (ow%4==0).
    // Tail clamps hi-load to cols 254..255 (in-row, values unused).
    float xin[C][K][6];
    #pragma unroll
    for (int c = 0; c < C; ++c) {
        #pragma unroll
        for (int kh = 0; kh < K; ++kh) {
            const float* xr = xb + ((size_t)c * H + (oh + kh)) * W + ow;
            vfloat4 lo = *reinterpret_cast<const vfloat4*>(xr);
            const float* xr2 = xr + (tail ? 2 : 4);
            vfloat2 hi = *reinterpret_cast<const vfloat2*>(xr2);
            xin[c][kh][0] = lo.x; xin[c][kh][1] = lo.y;
            xin[c][kh][2] = lo.z; xin[c][kh][3] = lo.w;
            xin[c][kh][4] = hi.x; xin[c][kh][5] = hi.y;
        }
    }

    #pragma unroll
    for (int oc = 0; oc < OC; ++oc) {
        const float* wp = w + oc * (C * K * K);
        float b  = bias[oc];        // uniform -> scalar load
        float a0 = b, a1 = b, a2 = b, a3 = b;
        #pragma unroll
        for (int c = 0; c < C; ++c) {
            #pragma unroll
            for (int kh = 0; kh < K; ++kh) {
                float w0 = wp[(c * K + kh) * K + 0];
                float w1 = wp[(c * K + kh) * K + 1];
                float w2 = wp[(c * K + kh) * K + 2];
                a0 += xin[c][kh][0] * w0 + xin[c][kh][1] * w1 + xin[c][kh][2] * w2;
                a1 += xin[c][kh][1] * w0 + xin[c][kh][2] * w1 + xin[c][kh][3] * w2;
                a2 += xin[c][kh][2] * w0 + xin[c][kh][3] * w1 + xin[c][kh][4] * w2;
                a3 += xin[c][kh][3] * w0 + xin[c][kh][4] * w1 + xin[c][kh][5] * w2;
            }
        }
        float* ob = out + (((size_t)n * OC + oc) * OH + oh) * OW + ow;
        if (!tail) {
            vfloat4 v4 = {a0, a1, a2, a3};
            __builtin_nontemporal_store(v4, reinterpret_cast<vfloat4*>(ob));
        } else {
            vfloat2 v2 = {a0, a1};
            __builtin_nontemporal_store(v2, reinterpret_cast<vfloat2*>(ob));
        }
    }
}

extern "C" void kernel_launch(void* const* d_in, const int* in_sizes, int n_in,
                              void* d_out, int out_size, void* d_ws, size_t ws_size,
                              hipStream_t stream) {
    const float* x    = (const float*)d_in[0];
    const float* w    = (const float*)d_in[1];
    const float* bias = (const float*)d_in[2];
    float* out        = (float*)d_out;

    conv3x3_kernel<<<NBLOCKS, 256, 0, stream>>>(x, w, bias, out);
}